// Round 4
// baseline (7319.874 us; speedup 1.0000x reference)
//
#include <hip/hip_runtime.h>
#include <cstddef>

#define BDIM 32
#define LEN 32
#define DD 384
#define NCELLS 528

typedef _Float16 h16;
typedef __attribute__((ext_vector_type(8))) _Float16 v8h;
typedef __attribute__((ext_vector_type(4))) float v4f;

__device__ __forceinline__ int offf(int k) { return k * 32 - ((k * (k - 1)) >> 1); }
static inline int offh(int k) { return k * 32 - ((k * (k - 1)) >> 1); }

__device__ __forceinline__ float sigma_h_f(float x) {
  float s = 1.0f / (1.0f + __expf(-x));      // sigmoid
  float r = sqrtf(s);
  float e2 = __expf(2.0f * r);
  float th = 1.0f - 2.0f / (e2 + 1.0f);      // tanh(r), r in (0,1)
  return x * th;
}

__device__ __forceinline__ size_t rowbase(int r, int gLs, int gOff) {
  if (gLs == 0) return (size_t)r;
  int b = r / gLs;
  int p = r - b * gLs;
  return (size_t)b * NCELLS + gOff + p;
}

// ---------------------------------------------------------------------------
// pack4: fp32 transposed weights (WCt, OW0t, LWt) + pre-split f16 hi/lo
// transposed W2 / out_W2 + zero score arrays.
__global__ __launch_bounds__(256) void pack4_k(
    const float* __restrict__ w0, const float* __restrict__ w1,
    const float* __restrict__ bi, const float* __restrict__ ow1,
    const float* __restrict__ obi, const float* __restrict__ w2,
    const float* __restrict__ ow2, const float* __restrict__ ow0,
    const float* __restrict__ lw,
    float* __restrict__ WCt, float* __restrict__ OW0t, float* __restrict__ LWt,
    h16* __restrict__ W2h, h16* __restrict__ W2l,
    h16* __restrict__ OW2h, h16* __restrict__ OW2l,
    float* __restrict__ isp, float* __restrict__ osp) {
  int i = blockIdx.x * 256 + threadIdx.x;
  if (i < 1920 * 384) {
    int n = i / 384, k = i - n * 384;
    int sel = n / 384, c = n - sel * 384;
    const float* src = sel == 0 ? w0 : sel == 1 ? w1 : sel == 2 ? bi
                       : sel == 3 ? ow1 : obi;
    WCt[i] = src[k * 384 + c];
  }
  if (i < 384 * 384) {
    int n = i / 384, k = i - n * 384;
    OW0t[i] = ow0[k * 384 + n];
    LWt[i]  = lw[k * 384 + n];
    float v = w2[k * 384 + n];
    h16 hh = (h16)v;
    W2h[i] = hh; W2l[i] = (h16)(v - (float)hh);
    v = ow2[k * 384 + n];
    hh = (h16)v;
    OW2h[i] = hh; OW2l[i] = (h16)(v - (float)hh);
  }
  if (i < BDIM * NCELLS) { isp[i] = 0.0f; osp[i] = 0.0f; }
}

// ---------------------------------------------------------------------------
// Split-f16 MFMA GEMM (proven round-3 version) for leaf / PC / P0.
__global__ __launch_bounds__(256) void gemm32s(
    const float* __restrict__ A, const float* __restrict__ Wt,
    const float* __restrict__ bias, float* __restrict__ C,
    int M, int N, int act, int gLs, int gOff) {
  __shared__ h16 Ah[64][40], Al[64][40];
  __shared__ h16 Bh[128][40], Bl[128][40];
  int tid = threadIdx.x;
  int w = tid >> 6, lane = tid & 63;
  int m0 = blockIdx.x * 64, n0 = blockIdx.y * 128;
  int r = lane & 15, q = lane >> 4;

  v4f acc[4][2];
#pragma unroll
  for (int i = 0; i < 4; ++i)
#pragma unroll
    for (int j = 0; j < 2; ++j) acc[i][j] = (v4f){0.f, 0.f, 0.f, 0.f};

  int sar = tid >> 2;
  int sak = (tid & 3) << 3;
  const float* Aptr = nullptr;
  if (m0 + sar < M) Aptr = A + rowbase(m0 + sar, gLs, gOff) * (size_t)DD;
  int sbc = tid >> 1;
  int sbk = (tid & 1) << 4;
  const float* Bptr = Wt + (size_t)(n0 + sbc) * DD;

  for (int k0 = 0; k0 < DD; k0 += 32) {
    float4 a0 = make_float4(0.f, 0.f, 0.f, 0.f), a1 = a0;
    if (Aptr) {
      a0 = *reinterpret_cast<const float4*>(Aptr + k0 + sak);
      a1 = *reinterpret_cast<const float4*>(Aptr + k0 + sak + 4);
    }
    float4 b0 = *reinterpret_cast<const float4*>(Bptr + k0 + sbk);
    float4 b1 = *reinterpret_cast<const float4*>(Bptr + k0 + sbk + 4);
    float4 b2 = *reinterpret_cast<const float4*>(Bptr + k0 + sbk + 8);
    float4 b3 = *reinterpret_cast<const float4*>(Bptr + k0 + sbk + 12);
    __syncthreads();
    {
      float av[8] = {a0.x, a0.y, a0.z, a0.w, a1.x, a1.y, a1.z, a1.w};
      v8h hi, lo;
#pragma unroll
      for (int t = 0; t < 8; ++t) {
        h16 h = (h16)av[t];
        hi[t] = h;
        lo[t] = (h16)(av[t] - (float)h);
      }
      *reinterpret_cast<v8h*>(&Ah[sar][sak]) = hi;
      *reinterpret_cast<v8h*>(&Al[sar][sak]) = lo;
    }
    {
      float bv[16] = {b0.x, b0.y, b0.z, b0.w, b1.x, b1.y, b1.z, b1.w,
                      b2.x, b2.y, b2.z, b2.w, b3.x, b3.y, b3.z, b3.w};
      v8h hi0, lo0, hi1, lo1;
#pragma unroll
      for (int t = 0; t < 8; ++t) {
        h16 h = (h16)bv[t];
        hi0[t] = h;
        lo0[t] = (h16)(bv[t] - (float)h);
      }
#pragma unroll
      for (int t = 0; t < 8; ++t) {
        h16 h = (h16)bv[8 + t];
        hi1[t] = h;
        lo1[t] = (h16)(bv[8 + t] - (float)h);
      }
      *reinterpret_cast<v8h*>(&Bh[sbc][sbk]) = hi0;
      *reinterpret_cast<v8h*>(&Bl[sbc][sbk]) = lo0;
      *reinterpret_cast<v8h*>(&Bh[sbc][sbk + 8]) = hi1;
      *reinterpret_cast<v8h*>(&Bl[sbc][sbk + 8]) = lo1;
    }
    __syncthreads();
    v8h afh[4], afl[4], bfh[2], bfl[2];
#pragma unroll
    for (int i = 0; i < 4; ++i) {
      afh[i] = *reinterpret_cast<const v8h*>(&Ah[i * 16 + r][q * 8]);
      afl[i] = *reinterpret_cast<const v8h*>(&Al[i * 16 + r][q * 8]);
    }
#pragma unroll
    for (int j = 0; j < 2; ++j) {
      bfh[j] = *reinterpret_cast<const v8h*>(&Bh[w * 32 + j * 16 + r][q * 8]);
      bfl[j] = *reinterpret_cast<const v8h*>(&Bl[w * 32 + j * 16 + r][q * 8]);
    }
#pragma unroll
    for (int i = 0; i < 4; ++i)
#pragma unroll
      for (int j = 0; j < 2; ++j) {
        acc[i][j] = __builtin_amdgcn_mfma_f32_16x16x32_f16(afl[i], bfh[j], acc[i][j], 0, 0, 0);
        acc[i][j] = __builtin_amdgcn_mfma_f32_16x16x32_f16(afh[i], bfl[j], acc[i][j], 0, 0, 0);
        acc[i][j] = __builtin_amdgcn_mfma_f32_16x16x32_f16(afh[i], bfh[j], acc[i][j], 0, 0, 0);
      }
  }

#pragma unroll
  for (int i = 0; i < 4; ++i) {
#pragma unroll
    for (int reg = 0; reg < 4; ++reg) {
      int rr = m0 + i * 16 + q * 4 + reg;
      if (rr >= M) continue;
      size_t cb = rowbase(rr, gLs, gOff) * (size_t)N;
#pragma unroll
      for (int j = 0; j < 2; ++j) {
        int col = n0 + w * 32 + j * 16 + r;
        float v = acc[i][j][reg];
        if (bias) v += bias[col];
        if (act) v = sigma_h_f(v);
        C[cb + col] = v;
      }
    }
  }
}

// ---------------------------------------------------------------------------
// fxc: fused per-level kernel. Block = K groups of P pairs (K*P <= 64 rows).
// Phases: scores+softmax+sbar -> H built on-the-fly into split-f16 LDS ->
// 64x384 MFMA GEMM (two B passes: hi then lo) -> sigma_h/p-weight/group
// reduce -> LayerNorm -> write ih/oh row.
// mode 0 = inside (P = L), mode 1 = outside (P = 31 - L).
__global__ __launch_bounds__(256) void fxc(
    const float* __restrict__ PC, const float* __restrict__ P0arr,
    const float* __restrict__ vArr,                 // ih (mode0) / oh (mode1)
    const float* __restrict__ sU, const float* __restrict__ sV,
    float* __restrict__ outH, float* __restrict__ outS,
    const h16* __restrict__ Wh, const h16* __restrict__ Wl,
    const float* __restrict__ B0a, const float* __restrict__ B1a,
    const float* __restrict__ lng, const float* __restrict__ lnb,
    int mode, int L, int P, int Ls, int offL, int K) {
  __shared__ h16 Ah[64][40], Al[64][40];   // split A tiles [row][k], pad->80B
  __shared__ h16 Bs[384][40];              // one of Bh/Bl per pass
  __shared__ float hbar[8][388];
  __shared__ float scs[64], pbuf[64];
  __shared__ int posg[8], bg[8], rgl[64];

  int tid = threadIdx.x;
  int w = tid >> 6, lane = tid & 63;
  int q = lane >> 4, r = lane & 15;
  int blk = blockIdx.x;
  int Gtot = BDIM * Ls;
  int Kact = K; if (blk * K + Kact > Gtot) Kact = Gtot - blk * K;
  int Mact = Kact * P;

  // phase 0: metadata + zeros
  if (tid < K) {
    int g = blk * K + tid;
    if (g < Gtot) { posg[tid] = g % Ls; bg[tid] = g / Ls; }
  }
  if (tid < 64) { pbuf[tid] = 0.0f; rgl[tid] = tid / P; }
  for (int i = tid; i < 8 * 388; i += 256) ((float*)hbar)[i] = 0.0f;
  __syncthreads();

  // phase 1: scores
  for (int s = w; s < Mact; s += 4) {
    int kg = s / P, n = s - kg * P;
    int pos = posg[kg];
    size_t cb = (size_t)bg[kg] * NCELLS;
    int uc, vc;
    if (mode == 0) {
      uc = offf(n) + pos;
      vc = offf(P - 1 - n) + pos + n + 1;
    } else {
      int cnt0 = 31 - pos - L;
      if (n < cnt0) { vc = offf(L + n + 1) + pos; uc = offf(n) + pos + L + 1; }
      else { int s2 = n - cnt0; vc = offf(L + s2 + 1) + pos - s2 - 1; uc = offf(s2) + pos - s2 - 1; }
    }
    const float* u = PC + (cb + uc) * 1920 + (mode ? 1536 : 768);
    const float* vv = vArr + (cb + vc) * (size_t)DD;
    float sdot = 0.0f;
#pragma unroll
    for (int jj = 0; jj < 6; ++jj) sdot += u[lane + 64 * jj] * vv[lane + 64 * jj];
#pragma unroll
    for (int o = 32; o; o >>= 1) sdot += __shfl_xor(sdot, o, 64);
    if (lane == 0) scs[s] = sdot + sU[cb + uc] + sV[cb + vc];
  }
  __syncthreads();

  // phase 2: softmax + sbar per group
  for (int kg = w; kg < Kact; kg += 4) {
    int base = kg * P;
    float v = (lane < P) ? scs[base + lane] : -3.0e38f;
    float m = v;
#pragma unroll
    for (int o = 32; o; o >>= 1) m = fmaxf(m, __shfl_xor(m, o, 64));
    float e = (lane < P) ? __expf(v - m) : 0.0f;
    float S = e;
#pragma unroll
    for (int o = 32; o; o >>= 1) S += __shfl_xor(S, o, 64);
    float pn = e / S;
    if (lane < P) pbuf[base + lane] = pn;
    float sb = (lane < P) ? pn * v : 0.0f;
#pragma unroll
    for (int o = 32; o; o >>= 1) sb += __shfl_xor(sb, o, 64);
    if (lane == 0) outS[(size_t)bg[kg] * NCELLS + offL + posg[kg]] = sb;
  }
  __syncthreads();

  // staging pointers (per thread, fixed row)
  int srow = tid >> 2, skc = (tid & 3) << 3;
  bool valid = srow < Mact;
  const float* p1 = nullptr;
  const float* p2 = nullptr;
  if (valid) {
    int kg = rgl[srow], n = srow - kg * P;
    int pos = posg[kg];
    size_t cb = (size_t)bg[kg] * NCELLS;
    if (mode == 0) {
      int lc = offf(n) + pos;
      int rc = offf(P - 1 - n) + pos + n + 1;
      p1 = PC + (cb + lc) * 1920;          // A0[l]
      p2 = PC + (cb + rc) * 1920 + 384;    // A1[r]
    } else {
      int cnt0 = 31 - pos - L, par, sib;
      if (n < cnt0) { par = offf(L + n + 1) + pos; sib = offf(n) + pos + L + 1; }
      else { int s2 = n - cnt0; par = offf(L + s2 + 1) + pos - s2 - 1; sib = offf(s2) + pos - s2 - 1; }
      p1 = P0arr + (cb + par) * (size_t)DD;  // P0[par]
      p2 = PC + (cb + sib) * 1920 + 1152;    // S1[sib]
    }
  }

  v4f acc[4][6];
#pragma unroll
  for (int i = 0; i < 4; ++i)
#pragma unroll
    for (int jj = 0; jj < 6; ++jj) acc[i][jj] = (v4f){0.f, 0.f, 0.f, 0.f};

  // GEMM pass 0: B = Wh, MFMAs: Al*Bh + Ah*Bh
  for (int k0 = 0; k0 < DD; k0 += 32) {
    __syncthreads();
    v8h hi = (v8h)(h16)0.f, lo = (v8h)(h16)0.f;
    if (valid) {
      float4 x0 = *reinterpret_cast<const float4*>(p1 + k0 + skc);
      float4 x1 = *reinterpret_cast<const float4*>(p1 + k0 + skc + 4);
      float4 y0 = *reinterpret_cast<const float4*>(p2 + k0 + skc);
      float4 y1 = *reinterpret_cast<const float4*>(p2 + k0 + skc + 4);
      float4 c0 = *reinterpret_cast<const float4*>(B0a + k0 + skc);
      float4 c1 = *reinterpret_cast<const float4*>(B0a + k0 + skc + 4);
      float e[8] = {x0.x + y0.x + c0.x, x0.y + y0.y + c0.y,
                    x0.z + y0.z + c0.z, x0.w + y0.w + c0.w,
                    x1.x + y1.x + c1.x, x1.y + y1.y + c1.y,
                    x1.z + y1.z + c1.z, x1.w + y1.w + c1.w};
#pragma unroll
      for (int t = 0; t < 8; ++t) {
        float h = sigma_h_f(e[t]);
        h16 hh = (h16)h;
        hi[t] = hh;
        lo[t] = (h16)(h - (float)hh);
      }
    }
    *reinterpret_cast<v8h*>(&Ah[srow][skc]) = hi;
    *reinterpret_cast<v8h*>(&Al[srow][skc]) = lo;
#pragma unroll
    for (int i2 = 0; i2 < 6; ++i2) {
      int c = tid + i2 * 256;
      int n2 = c >> 2, kc2 = (c & 3) << 3;
      *reinterpret_cast<v8h*>(&Bs[n2][kc2]) =
          *reinterpret_cast<const v8h*>(Wh + (size_t)n2 * DD + k0 + kc2);
    }
    __syncthreads();
    v8h afh[4], afl[4], bf[6];
#pragma unroll
    for (int i = 0; i < 4; ++i) {
      afh[i] = *reinterpret_cast<const v8h*>(&Ah[i * 16 + r][q * 8]);
      afl[i] = *reinterpret_cast<const v8h*>(&Al[i * 16 + r][q * 8]);
    }
#pragma unroll
    for (int jj = 0; jj < 6; ++jj)
      bf[jj] = *reinterpret_cast<const v8h*>(&Bs[w * 96 + jj * 16 + r][q * 8]);
#pragma unroll
    for (int i = 0; i < 4; ++i)
#pragma unroll
      for (int jj = 0; jj < 6; ++jj) {
        acc[i][jj] = __builtin_amdgcn_mfma_f32_16x16x32_f16(afl[i], bf[jj], acc[i][jj], 0, 0, 0);
        acc[i][jj] = __builtin_amdgcn_mfma_f32_16x16x32_f16(afh[i], bf[jj], acc[i][jj], 0, 0, 0);
      }
  }

  // GEMM pass 1: B = Wl, MFMA: Ah*Bl
  for (int k0 = 0; k0 < DD; k0 += 32) {
    __syncthreads();
    v8h hi = (v8h)(h16)0.f;
    if (valid) {
      float4 x0 = *reinterpret_cast<const float4*>(p1 + k0 + skc);
      float4 x1 = *reinterpret_cast<const float4*>(p1 + k0 + skc + 4);
      float4 y0 = *reinterpret_cast<const float4*>(p2 + k0 + skc);
      float4 y1 = *reinterpret_cast<const float4*>(p2 + k0 + skc + 4);
      float4 c0 = *reinterpret_cast<const float4*>(B0a + k0 + skc);
      float4 c1 = *reinterpret_cast<const float4*>(B0a + k0 + skc + 4);
      float e[8] = {x0.x + y0.x + c0.x, x0.y + y0.y + c0.y,
                    x0.z + y0.z + c0.z, x0.w + y0.w + c0.w,
                    x1.x + y1.x + c1.x, x1.y + y1.y + c1.y,
                    x1.z + y1.z + c1.z, x1.w + y1.w + c1.w};
#pragma unroll
      for (int t = 0; t < 8; ++t) hi[t] = (h16)sigma_h_f(e[t]);
    }
    *reinterpret_cast<v8h*>(&Ah[srow][skc]) = hi;
#pragma unroll
    for (int i2 = 0; i2 < 6; ++i2) {
      int c = tid + i2 * 256;
      int n2 = c >> 2, kc2 = (c & 3) << 3;
      *reinterpret_cast<v8h*>(&Bs[n2][kc2]) =
          *reinterpret_cast<const v8h*>(Wl + (size_t)n2 * DD + k0 + kc2);
    }
    __syncthreads();
    v8h afh[4], bf[6];
#pragma unroll
    for (int i = 0; i < 4; ++i)
      afh[i] = *reinterpret_cast<const v8h*>(&Ah[i * 16 + r][q * 8]);
#pragma unroll
    for (int jj = 0; jj < 6; ++jj)
      bf[jj] = *reinterpret_cast<const v8h*>(&Bs[w * 96 + jj * 16 + r][q * 8]);
#pragma unroll
    for (int i = 0; i < 4; ++i)
#pragma unroll
      for (int jj = 0; jj < 6; ++jj)
        acc[i][jj] = __builtin_amdgcn_mfma_f32_16x16x32_f16(afh[i], bf[jj], acc[i][jj], 0, 0, 0);
  }

  // epilogue: xc = sigma_h(acc + B1); hbar[kg] += p[row] * xc
  float b1v[6];
#pragma unroll
  for (int jj = 0; jj < 6; ++jj) b1v[jj] = B1a[w * 96 + jj * 16 + r];
#pragma unroll
  for (int i = 0; i < 4; ++i)
#pragma unroll
    for (int reg = 0; reg < 4; ++reg) {
      int row = i * 16 + q * 4 + reg;
      if (row < Mact) {
        float pw = pbuf[row];
        int kg = rgl[row];
#pragma unroll
        for (int jj = 0; jj < 6; ++jj) {
          float v = sigma_h_f(acc[i][jj][reg] + b1v[jj]);
          atomicAdd(&hbar[kg][w * 96 + jj * 16 + r], pw * v);
        }
      }
    }
  __syncthreads();

  // LayerNorm per group + store
  for (int kg = w; kg < Kact; kg += 4) {
    float vals[6];
    float sum = 0.0f;
#pragma unroll
    for (int jj = 0; jj < 6; ++jj) { vals[jj] = hbar[kg][lane + 64 * jj]; sum += vals[jj]; }
#pragma unroll
    for (int o = 32; o; o >>= 1) sum += __shfl_xor(sum, o, 64);
    float mean = sum * (1.0f / 384.0f);
    float qv = 0.0f;
#pragma unroll
    for (int jj = 0; jj < 6; ++jj) { float d = vals[jj] - mean; qv += d * d; }
#pragma unroll
    for (int o = 32; o; o >>= 1) qv += __shfl_xor(qv, o, 64);
    float inv = rsqrtf(qv * (1.0f / 384.0f) + 1e-5f);
    size_t cell = (size_t)bg[kg] * NCELLS + offL + posg[kg];
    float* out = outH + cell * DD;
#pragma unroll
    for (int jj = 0; jj < 6; ++jj) {
      int c = lane + 64 * jj;
      out[c] = (vals[jj] - mean) * inv * lng[c] + lnb[c];
    }
  }
}

// ---------------------------------------------------------------------------
// K3 (leaf only): hbar = LN(XC row) -> ih cell.
__global__ __launch_bounds__(128) void k3_red_ln(
    const float* __restrict__ XC, const float* __restrict__ Pw,
    const float* __restrict__ lng, const float* __restrict__ lnb,
    float* __restrict__ outArr, int L, int Ls, int offL) {
  int g = blockIdx.x;
  int b = g / Ls, pos = g - b * Ls;
  int tid = threadIdx.x;
  float a0 = 0, a1 = 0, a2 = 0;
  const float* base = XC + (size_t)g * L * DD;
  for (int n = 0; n < L; ++n) {
    float pw = Pw ? Pw[(size_t)g * L + n] : 1.0f;
    const float* row = base + (size_t)n * DD;
    a0 += pw * row[tid];
    a1 += pw * row[tid + 128];
    a2 += pw * row[tid + 256];
  }
  int lane = tid & 63, wv = tid >> 6;
  float s = a0 + a1 + a2;
#pragma unroll
  for (int o = 32; o; o >>= 1) s += __shfl_xor(s, o, 64);
  __shared__ float r1[2], r2[2];
  if (lane == 0) r1[wv] = s;
  __syncthreads();
  float mean = (r1[0] + r1[1]) * (1.0f / 384.0f);
  float d0 = a0 - mean, d1 = a1 - mean, d2 = a2 - mean;
  float q = d0 * d0 + d1 * d1 + d2 * d2;
#pragma unroll
  for (int o = 32; o; o >>= 1) q += __shfl_xor(q, o, 64);
  if (lane == 0) r2[wv] = q;
  __syncthreads();
  float var = (r2[0] + r2[1]) * (1.0f / 384.0f);
  float inv = rsqrtf(var + 1e-5f);
  float* out = outArr + ((size_t)b * NCELLS + offL + pos) * DD;
  out[tid]       = d0 * inv * lng[tid]       + lnb[tid];
  out[tid + 128] = d1 * inv * lng[tid + 128] + lnb[tid + 128];
  out[tid + 256] = d2 * inv * lng[tid + 256] + lnb[tid + 256];
}

// ---------------------------------------------------------------------------
// Root: oh[b][527] = LN(root_h), P0[b][527] = LN(root_h) @ out_W0.
__global__ __launch_bounds__(384) void root_k(
    const float* __restrict__ rooth, const float* __restrict__ lng,
    const float* __restrict__ lnb, const float* __restrict__ W0,
    float* __restrict__ ohp, float* __restrict__ P0) {
  int tid = threadIdx.x;
  int lane = tid & 63, wv = tid >> 6;
  __shared__ float rl[384];
  __shared__ float r1[6], r2[6];
  float x = rooth[tid];
  float s = x;
#pragma unroll
  for (int o = 32; o; o >>= 1) s += __shfl_xor(s, o, 64);
  if (lane == 0) r1[wv] = s;
  __syncthreads();
  float mean = (r1[0] + r1[1] + r1[2] + r1[3] + r1[4] + r1[5]) * (1.0f / 384.0f);
  float d = x - mean;
  float q = d * d;
#pragma unroll
  for (int o = 32; o; o >>= 1) q += __shfl_xor(q, o, 64);
  if (lane == 0) r2[wv] = q;
  __syncthreads();
  float var = (r2[0] + r2[1] + r2[2] + r2[3] + r2[4] + r2[5]) * (1.0f / 384.0f);
  float inv = rsqrtf(var + 1e-5f);
  float v = d * inv * lng[tid] + lnb[tid];
  rl[tid] = v;
  __syncthreads();
  for (int b2 = 0; b2 < BDIM; ++b2)
    ohp[((size_t)b2 * NCELLS + 527) * DD + tid] = v;
  float acc = 0.0f;
  for (int d2 = 0; d2 < 384; ++d2) acc += rl[d2] * W0[(size_t)d2 * 384 + tid];
  for (int b2 = 0; b2 < BDIM; ++b2)
    P0[((size_t)b2 * NCELLS + 527) * DD + tid] = acc;
}

// ---------------------------------------------------------------------------
extern "C" void kernel_launch(void* const* d_in, const int* in_sizes, int n_in,
                              void* d_out, int out_size, void* d_ws, size_t ws_size,
                              hipStream_t stream) {
  const float* x        = (const float*)d_in[0];
  const float* leaf_W   = (const float*)d_in[1];
  const float* leaf_b   = (const float*)d_in[2];
  const float* in_ln_g  = (const float*)d_in[3];
  const float* in_ln_b  = (const float*)d_in[4];
  const float* out_ln_g = (const float*)d_in[5];
  const float* out_ln_b = (const float*)d_in[6];
  const float* root_h   = (const float*)d_in[7];
  const float* in_bi    = (const float*)d_in[8];
  const float* out_bi   = (const float*)d_in[9];
  const float* in_W0    = (const float*)d_in[10];
  const float* in_W1    = (const float*)d_in[11];
  const float* in_B0    = (const float*)d_in[12];
  const float* in_W2    = (const float*)d_in[13];
  const float* in_B1    = (const float*)d_in[14];
  const float* out_W0   = (const float*)d_in[15];
  const float* out_W1   = (const float*)d_in[16];
  const float* out_B0   = (const float*)d_in[17];
  const float* out_W2   = (const float*)d_in[18];
  const float* out_B1   = (const float*)d_in[19];

  float* ih  = (float*)d_out;
  float* isp = ih + (size_t)BDIM * NCELLS * DD;
  float* oh  = isp + (size_t)BDIM * NCELLS;
  float* osp = oh + (size_t)BDIM * NCELLS * DD;

  float* PC   = (float*)d_ws;                               // 32*528*1920
  float* P0   = PC + (size_t)BDIM * NCELLS * 1920;          // 32*528*384
  float* WCt  = P0 + (size_t)BDIM * NCELLS * 384;           // 1920*384
  float* OW0t = WCt + (size_t)1920 * 384;                   // 384*384
  float* LWt  = OW0t + (size_t)384 * 384;                   // 384*384
  float* Lbuf = LWt + (size_t)384 * 384;                    // 1024*384
  h16* W2h  = (h16*)(Lbuf + (size_t)1024 * 384);            // 384*384 h16
  h16* W2l  = W2h + (size_t)384 * 384;
  h16* OW2h = W2l + (size_t)384 * 384;
  h16* OW2l = OW2h + (size_t)384 * 384;

  pack4_k<<<2880, 256, 0, stream>>>(in_W0, in_W1, in_bi, out_W1, out_bi,
                                    in_W2, out_W2, out_W0, leaf_W,
                                    WCt, OW0t, LWt, W2h, W2l, OW2h, OW2l,
                                    isp, osp);

  // leaf: T = sigma_h(x @ leaf_W + b); ih[level0] = LN(T); PC for leaves
  gemm32s<<<dim3(16, 3), 256, 0, stream>>>(x, LWt, leaf_b, Lbuf, 1024, 384, 1, 0, 0);
  k3_red_ln<<<1024, 128, 0, stream>>>(Lbuf, nullptr, in_ln_g, in_ln_b, ih, 1, 32, 0);
  gemm32s<<<dim3(16, 15), 256, 0, stream>>>(ih, WCt, nullptr, PC, 1024, 1920, 0, 32, 0);

  // inside pass
  for (int L = 1; L < LEN; ++L) {
    int P = L, Ls = LEN - L, G = BDIM * Ls, off = offh(L);
    int K = (P < 8) ? 8 : (64 / P);
    int Gk = (G + K - 1) / K;
    fxc<<<Gk, 256, 0, stream>>>(PC, nullptr, ih, isp, isp, ih, isp,
                                W2h, W2l, in_B0, in_B1, in_ln_g, in_ln_b,
                                0, L, P, Ls, off, K);
    gemm32s<<<dim3((G + 63) / 64, 15), 256, 0, stream>>>(ih, WCt, nullptr, PC, G, 1920, 0, Ls, off);
  }

  // root
  root_k<<<1, 384, 0, stream>>>(root_h, out_ln_g, out_ln_b, out_W0, oh, P0);

  // outside pass
  for (int L = LEN - 2; L >= 0; --L) {
    int P = LEN - 1 - L, Ls = LEN - L, G = BDIM * Ls, off = offh(L);
    int K = (P < 8) ? 8 : (64 / P);
    int Gk = (G + K - 1) / K;
    fxc<<<Gk, 256, 0, stream>>>(PC, P0, oh, isp, osp, oh, osp,
                                OW2h, OW2l, out_B0, out_B1, out_ln_g, out_ln_b,
                                1, L, P, Ls, off, K);
    if (L > 0)
      gemm32s<<<dim3((G + 63) / 64, 3), 256, 0, stream>>>(oh, OW0t, nullptr, P0, G, 384, 0, Ls, off);
  }
}

// Round 5
// 5358.923 us; speedup vs baseline: 1.3659x; 1.3659x over previous
//
#include <hip/hip_runtime.h>
#include <cstddef>

#define BDIM 32
#define LEN 32
#define DD 384
#define NCELLS 528

typedef _Float16 h16;
typedef __attribute__((ext_vector_type(8))) _Float16 v8h;
typedef __attribute__((ext_vector_type(4))) float v4f;

__device__ __forceinline__ int offf(int k) { return k * 32 - ((k * (k - 1)) >> 1); }
static inline int offh(int k) { return k * 32 - ((k * (k - 1)) >> 1); }

__device__ __forceinline__ float sigma_h_f(float x) {
  float s = 1.0f / (1.0f + __expf(-x));      // sigmoid
  float r = sqrtf(s);
  float e2 = __expf(2.0f * r);
  float th = 1.0f - 2.0f / (e2 + 1.0f);      // tanh(r), r in (0,1)
  return x * th;
}

__device__ __forceinline__ size_t rowbase(int r, int gLs, int gOff) {
  if (gLs == 0) return (size_t)r;
  int b = r / gLs;
  int p = r - b * gLs;
  return (size_t)b * NCELLS + gOff + p;
}

// ---------------------------------------------------------------------------
// pack5: fp32 transposed weights (WCt/OW0t/LWt) + pre-split h16 hi|lo
// transposed W2 / out_W2 ([n][768] = hi(384)|lo(384)) + zero score arrays.
__global__ __launch_bounds__(256) void pack5_k(
    const float* __restrict__ w0, const float* __restrict__ w1,
    const float* __restrict__ bi, const float* __restrict__ ow1,
    const float* __restrict__ obi, const float* __restrict__ w2,
    const float* __restrict__ ow2, const float* __restrict__ ow0,
    const float* __restrict__ lw,
    float* __restrict__ WCt, float* __restrict__ OW0t, float* __restrict__ LWt,
    h16* __restrict__ W2s, h16* __restrict__ OW2s,
    float* __restrict__ isp, float* __restrict__ osp) {
  int i = blockIdx.x * 256 + threadIdx.x;
  if (i < 1920 * 384) {
    int n = i / 384, k = i - n * 384;
    int sel = n / 384, c = n - sel * 384;
    const float* src = sel == 0 ? w0 : sel == 1 ? w1 : sel == 2 ? bi
                       : sel == 3 ? ow1 : obi;
    WCt[i] = src[k * 384 + c];
  }
  if (i < 384 * 384) {
    int n = i / 384, k = i - n * 384;
    OW0t[i] = ow0[k * 384 + n];
    LWt[i]  = lw[k * 384 + n];
    float v = w2[k * 384 + n];
    h16 hh = (h16)v;
    W2s[(size_t)n * 768 + k] = hh;
    W2s[(size_t)n * 768 + 384 + k] = (h16)(v - (float)hh);
    v = ow2[k * 384 + n];
    hh = (h16)v;
    OW2s[(size_t)n * 768 + k] = hh;
    OW2s[(size_t)n * 768 + 384 + k] = (h16)(v - (float)hh);
  }
  if (i < BDIM * NCELLS) { isp[i] = 0.0f; osp[i] = 0.0f; }
}

// ---------------------------------------------------------------------------
// Split-f16 MFMA GEMM (proven round-3 version) for leaf / PC / P0.
__global__ __launch_bounds__(256) void gemm32s(
    const float* __restrict__ A, const float* __restrict__ Wt,
    const float* __restrict__ bias, float* __restrict__ C,
    int M, int N, int act, int gLs, int gOff) {
  __shared__ h16 Ah[64][40], Al[64][40];
  __shared__ h16 Bh[128][40], Bl[128][40];
  int tid = threadIdx.x;
  int w = tid >> 6, lane = tid & 63;
  int m0 = blockIdx.x * 64, n0 = blockIdx.y * 128;
  int r = lane & 15, q = lane >> 4;

  v4f acc[4][2];
#pragma unroll
  for (int i = 0; i < 4; ++i)
#pragma unroll
    for (int j = 0; j < 2; ++j) acc[i][j] = (v4f){0.f, 0.f, 0.f, 0.f};

  int sar = tid >> 2;
  int sak = (tid & 3) << 3;
  const float* Aptr = nullptr;
  if (m0 + sar < M) Aptr = A + rowbase(m0 + sar, gLs, gOff) * (size_t)DD;
  int sbc = tid >> 1;
  int sbk = (tid & 1) << 4;
  const float* Bptr = Wt + (size_t)(n0 + sbc) * DD;

  for (int k0 = 0; k0 < DD; k0 += 32) {
    float4 a0 = make_float4(0.f, 0.f, 0.f, 0.f), a1 = a0;
    if (Aptr) {
      a0 = *reinterpret_cast<const float4*>(Aptr + k0 + sak);
      a1 = *reinterpret_cast<const float4*>(Aptr + k0 + sak + 4);
    }
    float4 b0 = *reinterpret_cast<const float4*>(Bptr + k0 + sbk);
    float4 b1 = *reinterpret_cast<const float4*>(Bptr + k0 + sbk + 4);
    float4 b2 = *reinterpret_cast<const float4*>(Bptr + k0 + sbk + 8);
    float4 b3 = *reinterpret_cast<const float4*>(Bptr + k0 + sbk + 12);
    __syncthreads();
    {
      float av[8] = {a0.x, a0.y, a0.z, a0.w, a1.x, a1.y, a1.z, a1.w};
      v8h hi, lo;
#pragma unroll
      for (int t = 0; t < 8; ++t) {
        h16 h = (h16)av[t];
        hi[t] = h;
        lo[t] = (h16)(av[t] - (float)h);
      }
      *reinterpret_cast<v8h*>(&Ah[sar][sak]) = hi;
      *reinterpret_cast<v8h*>(&Al[sar][sak]) = lo;
    }
    {
      float bv[16] = {b0.x, b0.y, b0.z, b0.w, b1.x, b1.y, b1.z, b1.w,
                      b2.x, b2.y, b2.z, b2.w, b3.x, b3.y, b3.z, b3.w};
      v8h hi0, lo0, hi1, lo1;
#pragma unroll
      for (int t = 0; t < 8; ++t) {
        h16 h = (h16)bv[t];
        hi0[t] = h;
        lo0[t] = (h16)(bv[t] - (float)h);
      }
#pragma unroll
      for (int t = 0; t < 8; ++t) {
        h16 h = (h16)bv[8 + t];
        hi1[t] = h;
        lo1[t] = (h16)(bv[8 + t] - (float)h);
      }
      *reinterpret_cast<v8h*>(&Bh[sbc][sbk]) = hi0;
      *reinterpret_cast<v8h*>(&Bl[sbc][sbk]) = lo0;
      *reinterpret_cast<v8h*>(&Bh[sbc][sbk + 8]) = hi1;
      *reinterpret_cast<v8h*>(&Bl[sbc][sbk + 8]) = lo1;
    }
    __syncthreads();
    v8h afh[4], afl[4], bfh[2], bfl[2];
#pragma unroll
    for (int i = 0; i < 4; ++i) {
      afh[i] = *reinterpret_cast<const v8h*>(&Ah[i * 16 + r][q * 8]);
      afl[i] = *reinterpret_cast<const v8h*>(&Al[i * 16 + r][q * 8]);
    }
#pragma unroll
    for (int j = 0; j < 2; ++j) {
      bfh[j] = *reinterpret_cast<const v8h*>(&Bh[w * 32 + j * 16 + r][q * 8]);
      bfl[j] = *reinterpret_cast<const v8h*>(&Bl[w * 32 + j * 16 + r][q * 8]);
    }
#pragma unroll
    for (int i = 0; i < 4; ++i)
#pragma unroll
      for (int j = 0; j < 2; ++j) {
        acc[i][j] = __builtin_amdgcn_mfma_f32_16x16x32_f16(afl[i], bfh[j], acc[i][j], 0, 0, 0);
        acc[i][j] = __builtin_amdgcn_mfma_f32_16x16x32_f16(afh[i], bfl[j], acc[i][j], 0, 0, 0);
        acc[i][j] = __builtin_amdgcn_mfma_f32_16x16x32_f16(afh[i], bfh[j], acc[i][j], 0, 0, 0);
      }
  }

#pragma unroll
  for (int i = 0; i < 4; ++i) {
#pragma unroll
    for (int reg = 0; reg < 4; ++reg) {
      int rr = m0 + i * 16 + q * 4 + reg;
      if (rr >= M) continue;
      size_t cb = rowbase(rr, gLs, gOff) * (size_t)N;
#pragma unroll
      for (int j = 0; j < 2; ++j) {
        int col = n0 + w * 32 + j * 16 + r;
        float v = acc[i][j][reg];
        if (bias) v += bias[col];
        if (act) v = sigma_h_f(v);
        C[cb + col] = v;
      }
    }
  }
}

// ---------------------------------------------------------------------------
// gemmsp: pure pre-split f16 MFMA GEMM for the XC pair-GEMM (the FLOP bulk).
// A[M][768] = hi|lo per row (from k1). Wt[384][768] = hi|lo (pre-split,
// transposed). C[M][384] = sigma_h(A@W^T + bias). 128x128x32 tiles, 4 waves.
// No conversion VALU in the k-loop; padded LDS => only free 2-way conflicts.
__global__ __launch_bounds__(256) void gemmsp(
    const h16* __restrict__ A, const h16* __restrict__ Wt,
    const float* __restrict__ bias, float* __restrict__ C, int M) {
  __shared__ h16 Ah[128][40], Al[128][40], Bh[128][40], Bl[128][40];
  int tid = threadIdx.x;
  int w = tid >> 6, lane = tid & 63;
  int r = lane & 15, q = lane >> 4;
  int m0 = blockIdx.x * 128, n0 = blockIdx.y * 128;

  v4f acc[8][2];
#pragma unroll
  for (int i = 0; i < 8; ++i)
#pragma unroll
    for (int j = 0; j < 2; ++j) acc[i][j] = (v4f){0.f, 0.f, 0.f, 0.f};

  int arow = tid >> 1;          // 0..127
  int akc = (tid & 1) << 4;     // 0 or 16 halves
  const h16* Aptr = (m0 + arow < M) ? A + (size_t)(m0 + arow) * 768 : nullptr;
  const h16* Bptr = Wt + (size_t)(n0 + arow) * 768;

  for (int k0 = 0; k0 < DD; k0 += 32) {
    v8h ah0 = (v8h)(h16)0.f, ah1 = ah0, al0 = ah0, al1 = ah0;
    if (Aptr) {
      ah0 = *reinterpret_cast<const v8h*>(Aptr + k0 + akc);
      ah1 = *reinterpret_cast<const v8h*>(Aptr + k0 + akc + 8);
      al0 = *reinterpret_cast<const v8h*>(Aptr + 384 + k0 + akc);
      al1 = *reinterpret_cast<const v8h*>(Aptr + 384 + k0 + akc + 8);
    }
    v8h bh0 = *reinterpret_cast<const v8h*>(Bptr + k0 + akc);
    v8h bh1 = *reinterpret_cast<const v8h*>(Bptr + k0 + akc + 8);
    v8h bl0 = *reinterpret_cast<const v8h*>(Bptr + 384 + k0 + akc);
    v8h bl1 = *reinterpret_cast<const v8h*>(Bptr + 384 + k0 + akc + 8);
    __syncthreads();
    *reinterpret_cast<v8h*>(&Ah[arow][akc])     = ah0;
    *reinterpret_cast<v8h*>(&Ah[arow][akc + 8]) = ah1;
    *reinterpret_cast<v8h*>(&Al[arow][akc])     = al0;
    *reinterpret_cast<v8h*>(&Al[arow][akc + 8]) = al1;
    *reinterpret_cast<v8h*>(&Bh[arow][akc])     = bh0;
    *reinterpret_cast<v8h*>(&Bh[arow][akc + 8]) = bh1;
    *reinterpret_cast<v8h*>(&Bl[arow][akc])     = bl0;
    *reinterpret_cast<v8h*>(&Bl[arow][akc + 8]) = bl1;
    __syncthreads();
    v8h afh[8], afl[8], bfh[2], bfl[2];
#pragma unroll
    for (int i = 0; i < 8; ++i) {
      afh[i] = *reinterpret_cast<const v8h*>(&Ah[i * 16 + r][q * 8]);
      afl[i] = *reinterpret_cast<const v8h*>(&Al[i * 16 + r][q * 8]);
    }
#pragma unroll
    for (int j = 0; j < 2; ++j) {
      bfh[j] = *reinterpret_cast<const v8h*>(&Bh[w * 32 + j * 16 + r][q * 8]);
      bfl[j] = *reinterpret_cast<const v8h*>(&Bl[w * 32 + j * 16 + r][q * 8]);
    }
#pragma unroll
    for (int i = 0; i < 8; ++i)
#pragma unroll
      for (int j = 0; j < 2; ++j) {
        acc[i][j] = __builtin_amdgcn_mfma_f32_16x16x32_f16(afl[i], bfh[j], acc[i][j], 0, 0, 0);
        acc[i][j] = __builtin_amdgcn_mfma_f32_16x16x32_f16(afh[i], bfl[j], acc[i][j], 0, 0, 0);
        acc[i][j] = __builtin_amdgcn_mfma_f32_16x16x32_f16(afh[i], bfh[j], acc[i][j], 0, 0, 0);
      }
  }

#pragma unroll
  for (int i = 0; i < 8; ++i) {
#pragma unroll
    for (int reg = 0; reg < 4; ++reg) {
      int rr = m0 + i * 16 + q * 4 + reg;
      if (rr >= M) continue;
      size_t cb = (size_t)rr * DD;
#pragma unroll
      for (int j = 0; j < 2; ++j) {
        int col = n0 + w * 32 + j * 16 + r;
        C[cb + col] = sigma_h_f(acc[i][j][reg] + bias[col]);
      }
    }
  }
}

// ---------------------------------------------------------------------------
// K1 inside: scores+softmax+sbar -> is_, and H rows written pre-split hi|lo.
__global__ __launch_bounds__(256) void k1_in(
    const float* __restrict__ PC, const float* __restrict__ ihp,
    float* __restrict__ isp, h16* __restrict__ Hs, float* __restrict__ Pw,
    const float* __restrict__ B0, int L, int Ls, int offL) {
  int g = blockIdx.x;
  int b = g / Ls, pos = g - b * Ls;
  int tid = threadIdx.x, lane = tid & 63, wv = tid >> 6;
  __shared__ float scs[32];
  size_t cb = (size_t)b * NCELLS;
  for (int n = wv; n < L; n += 4) {
    int lc = offf(n) + pos;
    int rc = offf(L - 1 - n) + pos + n + 1;
    const float* u = PC + (cb + lc) * 1920 + 768;   // Uin[l]
    const float* v = ihp + (cb + rc) * (size_t)DD;  // ih[r]
    float s = 0.0f;
#pragma unroll
    for (int jj = 0; jj < 6; ++jj) s += u[lane + 64 * jj] * v[lane + 64 * jj];
#pragma unroll
    for (int o = 32; o; o >>= 1) s += __shfl_xor(s, o, 64);
    if (lane == 0) scs[n] = s + isp[cb + lc] + isp[cb + rc];
  }
  __syncthreads();
  if (wv == 0) {
    float v = (lane < L) ? scs[lane] : -3.0e38f;
    float m = v;
#pragma unroll
    for (int o = 32; o; o >>= 1) m = fmaxf(m, __shfl_xor(m, o, 64));
    float e = (lane < L) ? __expf(v - m) : 0.0f;
    float S = e;
#pragma unroll
    for (int o = 32; o; o >>= 1) S += __shfl_xor(S, o, 64);
    float pn = e / S;
    if (lane < L) Pw[(size_t)g * L + lane] = pn;
    float sb = (lane < L) ? pn * v : 0.0f;
#pragma unroll
    for (int o = 32; o; o >>= 1) sb += __shfl_xor(sb, o, 64);
    if (lane == 0) isp[cb + offL + pos] = sb;
  }
  for (int n = 0; n < L; ++n) {
    int lc = offf(n) + pos;
    int rc = offf(L - 1 - n) + pos + n + 1;
    const float* A0r = PC + (cb + lc) * 1920;
    const float* A1r = PC + (cb + rc) * 1920 + 384;
    h16* hrow = Hs + ((size_t)g * L + n) * 768;
    for (int k = tid; k < DD; k += 256) {
      float h = sigma_h_f(A0r[k] + A1r[k] + B0[k]);
      h16 hh = (h16)h;
      hrow[k] = hh;
      hrow[384 + k] = (h16)(h - (float)hh);
    }
  }
}

// K1 outside.
__global__ __launch_bounds__(256) void k1_out(
    const float* __restrict__ PC, const float* __restrict__ P0,
    const float* __restrict__ ohp, const float* __restrict__ isp,
    float* __restrict__ osp, h16* __restrict__ Hs, float* __restrict__ Pw,
    const float* __restrict__ B0, int L, int Ls, int Nc, int offL) {
  int g = blockIdx.x;
  int b = g / Ls, pos = g - b * Ls;
  int tid = threadIdx.x, lane = tid & 63, wv = tid >> 6;
  __shared__ float scs[32];
  size_t cb = (size_t)b * NCELLS;
  int cnt0 = 31 - pos - L;
  for (int j = wv; j < Nc; j += 4) {
    int par, sib;
    if (j < cnt0) { par = offf(L + j + 1) + pos; sib = offf(j) + pos + L + 1; }
    else { int s2 = j - cnt0; par = offf(L + s2 + 1) + pos - s2 - 1; sib = offf(s2) + pos - s2 - 1; }
    const float* u = PC + (cb + sib) * 1920 + 1536;  // Uout[sib]
    const float* v = ohp + (cb + par) * (size_t)DD;  // oh[par]
    float s = 0.0f;
#pragma unroll
    for (int jj = 0; jj < 6; ++jj) s += u[lane + 64 * jj] * v[lane + 64 * jj];
#pragma unroll
    for (int o = 32; o; o >>= 1) s += __shfl_xor(s, o, 64);
    if (lane == 0) scs[j] = s + isp[cb + sib] + osp[cb + par];
  }
  __syncthreads();
  if (wv == 0) {
    float v = (lane < Nc) ? scs[lane] : -3.0e38f;
    float m = v;
#pragma unroll
    for (int o = 32; o; o >>= 1) m = fmaxf(m, __shfl_xor(m, o, 64));
    float e = (lane < Nc) ? __expf(v - m) : 0.0f;
    float S = e;
#pragma unroll
    for (int o = 32; o; o >>= 1) S += __shfl_xor(S, o, 64);
    float pn = e / S;
    if (lane < Nc) Pw[(size_t)g * Nc + lane] = pn;
    float sb = (lane < Nc) ? pn * v : 0.0f;
#pragma unroll
    for (int o = 32; o; o >>= 1) sb += __shfl_xor(sb, o, 64);
    if (lane == 0) osp[cb + offL + pos] = sb;
  }
  for (int j = 0; j < Nc; ++j) {
    int par, sib;
    if (j < cnt0) { par = offf(L + j + 1) + pos; sib = offf(j) + pos + L + 1; }
    else { int s2 = j - cnt0; par = offf(L + s2 + 1) + pos - s2 - 1; sib = offf(s2) + pos - s2 - 1; }
    const float* p0r = P0 + (cb + par) * (size_t)DD;
    const float* s1r = PC + (cb + sib) * 1920 + 1152;
    h16* hrow = Hs + ((size_t)g * Nc + j) * 768;
    for (int k = tid; k < DD; k += 256) {
      float h = sigma_h_f(p0r[k] + s1r[k] + B0[k]);
      h16 hh = (h16)h;
      hrow[k] = hh;
      hrow[384 + k] = (h16)(h - (float)hh);
    }
  }
}

// ---------------------------------------------------------------------------
// K3: hbar = LN(sum_n p[n]*XC[row n]) -> outArr cell. Pw==null => weight 1.
__global__ __launch_bounds__(128) void k3_red_ln(
    const float* __restrict__ XC, const float* __restrict__ Pw,
    const float* __restrict__ lng, const float* __restrict__ lnb,
    float* __restrict__ outArr, int L, int Ls, int offL) {
  int g = blockIdx.x;
  int b = g / Ls, pos = g - b * Ls;
  int tid = threadIdx.x;
  float a0 = 0, a1 = 0, a2 = 0;
  const float* base = XC + (size_t)g * L * DD;
  for (int n = 0; n < L; ++n) {
    float pw = Pw ? Pw[(size_t)g * L + n] : 1.0f;
    const float* row = base + (size_t)n * DD;
    a0 += pw * row[tid];
    a1 += pw * row[tid + 128];
    a2 += pw * row[tid + 256];
  }
  int lane = tid & 63, wv = tid >> 6;
  float s = a0 + a1 + a2;
#pragma unroll
  for (int o = 32; o; o >>= 1) s += __shfl_xor(s, o, 64);
  __shared__ float r1[2], r2[2];
  if (lane == 0) r1[wv] = s;
  __syncthreads();
  float mean = (r1[0] + r1[1]) * (1.0f / 384.0f);
  float d0 = a0 - mean, d1 = a1 - mean, d2 = a2 - mean;
  float q = d0 * d0 + d1 * d1 + d2 * d2;
#pragma unroll
  for (int o = 32; o; o >>= 1) q += __shfl_xor(q, o, 64);
  if (lane == 0) r2[wv] = q;
  __syncthreads();
  float var = (r2[0] + r2[1]) * (1.0f / 384.0f);
  float inv = rsqrtf(var + 1e-5f);
  float* out = outArr + ((size_t)b * NCELLS + offL + pos) * DD;
  out[tid]       = d0 * inv * lng[tid]       + lnb[tid];
  out[tid + 128] = d1 * inv * lng[tid + 128] + lnb[tid + 128];
  out[tid + 256] = d2 * inv * lng[tid + 256] + lnb[tid + 256];
}

// ---------------------------------------------------------------------------
// Root: oh[b][527] = LN(root_h), P0[b][527] = LN(root_h) @ out_W0.
__global__ __launch_bounds__(384) void root_k(
    const float* __restrict__ rooth, const float* __restrict__ lng,
    const float* __restrict__ lnb, const float* __restrict__ W0,
    float* __restrict__ ohp, float* __restrict__ P0) {
  int tid = threadIdx.x;
  int lane = tid & 63, wv = tid >> 6;
  __shared__ float rl[384];
  __shared__ float r1[6], r2[6];
  float x = rooth[tid];
  float s = x;
#pragma unroll
  for (int o = 32; o; o >>= 1) s += __shfl_xor(s, o, 64);
  if (lane == 0) r1[wv] = s;
  __syncthreads();
  float mean = (r1[0] + r1[1] + r1[2] + r1[3] + r1[4] + r1[5]) * (1.0f / 384.0f);
  float d = x - mean;
  float q = d * d;
#pragma unroll
  for (int o = 32; o; o >>= 1) q += __shfl_xor(q, o, 64);
  if (lane == 0) r2[wv] = q;
  __syncthreads();
  float var = (r2[0] + r2[1] + r2[2] + r2[3] + r2[4] + r2[5]) * (1.0f / 384.0f);
  float inv = rsqrtf(var + 1e-5f);
  float v = d * inv * lng[tid] + lnb[tid];
  rl[tid] = v;
  __syncthreads();
  for (int b2 = 0; b2 < BDIM; ++b2)
    ohp[((size_t)b2 * NCELLS + 527) * DD + tid] = v;
  float acc = 0.0f;
  for (int d2 = 0; d2 < 384; ++d2) acc += rl[d2] * W0[(size_t)d2 * 384 + tid];
  for (int b2 = 0; b2 < BDIM; ++b2)
    P0[((size_t)b2 * NCELLS + 527) * DD + tid] = acc;
}

// ---------------------------------------------------------------------------
extern "C" void kernel_launch(void* const* d_in, const int* in_sizes, int n_in,
                              void* d_out, int out_size, void* d_ws, size_t ws_size,
                              hipStream_t stream) {
  const float* x        = (const float*)d_in[0];
  const float* leaf_W   = (const float*)d_in[1];
  const float* leaf_b   = (const float*)d_in[2];
  const float* in_ln_g  = (const float*)d_in[3];
  const float* in_ln_b  = (const float*)d_in[4];
  const float* out_ln_g = (const float*)d_in[5];
  const float* out_ln_b = (const float*)d_in[6];
  const float* root_h   = (const float*)d_in[7];
  const float* in_bi    = (const float*)d_in[8];
  const float* out_bi   = (const float*)d_in[9];
  const float* in_W0    = (const float*)d_in[10];
  const float* in_W1    = (const float*)d_in[11];
  const float* in_B0    = (const float*)d_in[12];
  const float* in_W2    = (const float*)d_in[13];
  const float* in_B1    = (const float*)d_in[14];
  const float* out_W0   = (const float*)d_in[15];
  const float* out_W1   = (const float*)d_in[16];
  const float* out_B0   = (const float*)d_in[17];
  const float* out_W2   = (const float*)d_in[18];
  const float* out_B1   = (const float*)d_in[19];

  float* ih  = (float*)d_out;
  float* isp = ih + (size_t)BDIM * NCELLS * DD;
  float* oh  = isp + (size_t)BDIM * NCELLS;
  float* osp = oh + (size_t)BDIM * NCELLS * DD;

  float* PC   = (float*)d_ws;                               // 32*528*1920
  float* P0   = PC + (size_t)BDIM * NCELLS * 1920;          // 32*528*384
  float* XCb  = P0 + (size_t)BDIM * NCELLS * 384;           // 31744*384
  float* Pw   = XCb + (size_t)31744 * 384;                  // 31744
  float* WCt  = Pw + 31744;                                 // 1920*384
  float* OW0t = WCt + (size_t)1920 * 384;                   // 384*384
  float* LWt  = OW0t + (size_t)384 * 384;                   // 384*384
  float* Lbuf = LWt + (size_t)384 * 384;                    // 1024*384
  h16* Hs   = (h16*)(Lbuf + (size_t)1024 * 384);            // 31744*768 h16
  h16* W2s  = Hs + (size_t)31744 * 768;                     // 384*768 h16
  h16* OW2s = W2s + (size_t)384 * 768;                      // 384*768 h16

  pack5_k<<<2880, 256, 0, stream>>>(in_W0, in_W1, in_bi, out_W1, out_bi,
                                    in_W2, out_W2, out_W0, leaf_W,
                                    WCt, OW0t, LWt, W2s, OW2s, isp, osp);

  // leaf: T = sigma_h(x @ leaf_W + b); ih[level0] = LN(T); PC for leaves
  gemm32s<<<dim3(16, 3), 256, 0, stream>>>(x, LWt, leaf_b, Lbuf, 1024, 384, 1, 0, 0);
  k3_red_ln<<<1024, 128, 0, stream>>>(Lbuf, nullptr, in_ln_g, in_ln_b, ih, 1, 32, 0);
  gemm32s<<<dim3(16, 15), 256, 0, stream>>>(ih, WCt, nullptr, PC, 1024, 1920, 0, 32, 0);

  // inside pass
  for (int L = 1; L < LEN; ++L) {
    int Ls = LEN - L, G = BDIM * Ls, M = G * L, off = offh(L);
    k1_in<<<G, 256, 0, stream>>>(PC, ih, isp, Hs, Pw, in_B0, L, Ls, off);
    gemmsp<<<dim3((M + 127) / 128, 3), 256, 0, stream>>>(Hs, W2s, in_B1, XCb, M);
    k3_red_ln<<<G, 128, 0, stream>>>(XCb, Pw, in_ln_g, in_ln_b, ih, L, Ls, off);
    gemm32s<<<dim3((G + 63) / 64, 15), 256, 0, stream>>>(ih, WCt, nullptr, PC, G, 1920, 0, Ls, off);
  }

  // root
  root_k<<<1, 384, 0, stream>>>(root_h, out_ln_g, out_ln_b, out_W0, oh, P0);

  // outside pass
  for (int L = LEN - 2; L >= 0; --L) {
    int Ls = LEN - L, Nc = LEN - 1 - L, G = BDIM * Ls, M = G * Nc, off = offh(L);
    k1_out<<<G, 256, 0, stream>>>(PC, P0, oh, isp, osp, Hs, Pw, out_B0, L, Ls, Nc, off);
    gemmsp<<<dim3((M + 127) / 128, 3), 256, 0, stream>>>(Hs, OW2s, out_B1, XCb, M);
    k3_red_ln<<<G, 128, 0, stream>>>(XCb, Pw, out_ln_g, out_ln_b, oh, Nc, Ls, off);
    if (L > 0)
      gemm32s<<<dim3((G + 63) / 64, 3), 256, 0, stream>>>(oh, OW0t, nullptr, P0, G, 384, 0, Ls, off);
  }
}